// Round 4
// baseline (542.630 us; speedup 1.0000x reference)
//
#include <hip/hip_runtime.h>

#define EPS_ALPHA 1e-5f

// DeepPoly ReLU6 relaxation, all six outputs per neuron.
struct Relax { float cl, cu, dl, du, bl, bu; };

__device__ __forceinline__ Relax relax6(float l, float u) {
    // guarded denominators — identical to reference so all divisions are finite
    float den_ul = (u > l)    ? (u - l)    : 1.0f;
    float den_6l = (l < 6.0f) ? (6.0f - l) : 1.0f;
    float u_safe = (u > 0.0f) ? u          : 1.0f;

    bool mA = (u > 0.0f) && (u <= 6.0f) && (l >= 0.0f);  // stable active
    bool mB = (u > 0.0f) && (u <= 6.0f) && (l < 0.0f);   // crosses 0
    bool mC = (u > 6.0f) && (l <= 0.0f);                 // crosses 0 and 6
    bool mD = (u > 6.0f) && (l > 0.0f) && (l <= 6.0f);   // crosses 6
    bool mE = (l > 6.0f);                                // saturated

    float alpha_B = (u < -l) ? EPS_ALPHA : 1.0f;
    float lam_B   = u / den_ul;
    bool  upC     = ((u - 6.0f) < (6.0f - l));
    float aU_C = upC ? (6.0f / den_6l) : EPS_ALPHA;
    float aL_C = (u < -l) ? EPS_ALPHA : (6.0f / u_safe);
    float aU_D = upC ? 1.0f : EPS_ALPHA;
    float aL_D = (6.0f - l) / den_ul;

    Relax R;
    // masks mutually exclusive; non-selected reference terms are exact 0
    R.du = mA ? 1.0f : mB ? lam_B   : mC ? aU_C : mD ? aU_D : 0.0f;
    R.dl = mA ? 1.0f : mB ? alpha_B : mC ? aL_C : mD ? aL_D : 0.0f;
    R.bu = mB ? (-lam_B * l)
         : mC ? (6.0f * (1.0f - aU_C))
         : mD ? (6.0f * (1.0f - aU_D))
         : mE ? 6.0f : 0.0f;
    R.bl = mD ? (l * (1.0f - aL_D))
         : mE ? 6.0f : 0.0f;
    R.cu = mA ? u : mB ? u
         : mC ? (6.0f + aU_C * (u - 6.0f))
         : mD ? (6.0f + aU_D * (u - 6.0f))
         : mE ? 6.0f : 0.0f;
    R.cl = mA ? l
         : mB ? (alpha_B * l)
         : mC ? (aL_C * l)
         : mD ? l
         : mE ? 6.0f : 0.0f;
    return R;
}

// One fused pass writing every logical output float exactly once.
//   block [0, M)    -> A_l row bid       (zero row + diag, or bias row if r==n)
//   block [M, 2M)   -> A_u row bid-M
//   block 2M        -> cl vector
//   block 2M+1      -> cu vector
// Rows are contiguous M-float segments. M = 8193 is odd, so each row's 16B
// alignment phase differs; handled with scalar head/tail + aligned float4 body.
// Diagonal rows: zero-fill the whole row vectorized, barrier, then thread 0
// overwrites the single diagonal element (no per-chunk conditionals).
__global__ __launch_bounds__(256) void relu6_fused(
        const float* __restrict__ lower, const float* __restrict__ upper,
        float* __restrict__ out, int n) {
    const int tid = threadIdx.x;
    const long long M   = (long long)n + 1;
    const long long MM  = M * M;
    const long long bid = blockIdx.x;

    // ---------------- cl / cu vectors ----------------
    if (bid >= 2 * M) {
        const int which = (int)(bid - 2 * M);   // 0 -> cl, 1 -> cu
        float* dst = out + (long long)which * n;
        const int nv = n & ~3;
        for (int i = tid * 4; i < nv; i += 256 * 4) {
            float4 lv = *reinterpret_cast<const float4*>(lower + i);
            float4 uv = *reinterpret_cast<const float4*>(upper + i);
            Relax r0 = relax6(lv.x, uv.x), r1 = relax6(lv.y, uv.y),
                  r2 = relax6(lv.z, uv.z), r3 = relax6(lv.w, uv.w);
            float4 v;
            v.x = which ? r0.cu : r0.cl;
            v.y = which ? r1.cu : r1.cl;
            v.z = which ? r2.cu : r2.cl;
            v.w = which ? r3.cu : r3.cl;
            *reinterpret_cast<float4*>(dst + i) = v;
        }
        for (int i = nv + tid; i < n; i += 256) {
            Relax R = relax6(lower[i], upper[i]);
            dst[i] = which ? R.cu : R.cl;
        }
        return;
    }

    // ---------------- matrix rows ----------------
    const int       mat   = (bid >= M) ? 1 : 0;     // 0 -> A_l, 1 -> A_u
    const long long r     = bid - (mat ? M : 0);
    const long long start = 2LL * n + (mat ? MM : 0) + r * M;
    float* __restrict__ row = out + start;

    const int       head      = (int)((4 - (start & 3)) & 3);
    const long long tailStart = head + ((M - head) & ~3LL);   // 16B body end
    const long long tailLen   = M - tailStart;                // 0..3

    if (r < n) {
        // zero row, then fix up the diagonal element
        const float4 z = make_float4(0.f, 0.f, 0.f, 0.f);
        for (long long c = head + (long long)tid * 4; c < tailStart; c += 256 * 4)
            *reinterpret_cast<float4*>(row + c) = z;
        if (tid < head)    row[tid] = 0.0f;
        if (tid < tailLen) row[tailStart + tid] = 0.0f;
        __syncthreads();
        if (tid == 0) {
            Relax R = relax6(lower[r], upper[r]);
            row[r] = mat ? R.du : R.dl;
        }
    } else {
        // bias row (r == n): cols [0,n) = bias, col n = 1.0
        for (long long c = head + (long long)tid * 4; c < tailStart; c += 256 * 4) {
            float4 v;
            #pragma unroll
            for (int j = 0; j < 4; ++j) {
                long long cc = c + j;
                float val;
                if (cc >= n) {
                    val = 1.0f;                       // cc can only be n here
                } else {
                    Relax R = relax6(lower[cc], upper[cc]);
                    val = mat ? R.bu : R.bl;
                }
                (&v.x)[j] = val;
            }
            *reinterpret_cast<float4*>(row + c) = v;
        }
        if (tid < head) {
            long long c = tid;
            Relax R = relax6(lower[c], upper[c]);     // head cols are < n
            row[c] = mat ? R.bu : R.bl;
        }
        if (tid < tailLen) {
            long long c = tailStart + tid;
            float val;
            if (c >= n) val = 1.0f;
            else { Relax R = relax6(lower[c], upper[c]); val = mat ? R.bu : R.bl; }
            row[c] = val;
        }
    }
}

extern "C" void kernel_launch(void* const* d_in, const int* in_sizes, int n_in,
                              void* d_out, int out_size, void* d_ws, size_t ws_size,
                              hipStream_t stream) {
    const float* lower = (const float*)d_in[0];
    const float* upper = (const float*)d_in[1];
    float* out = (float*)d_out;
    int n = in_sizes[0];  // 8192

    // No memset: the fused kernel writes every logical output float exactly
    // once (zeros included) with coalesced float4 streaming stores. This
    // removes the separate 537 MB fill pass AND the scatter kernel's
    // partial-cacheline diagonal writes.
    const long long M = (long long)n + 1;
    const long long numBlocks = 2 * M + 2;   // 2M matrix rows + cl + cu
    relu6_fused<<<(int)numBlocks, 256, 0, stream>>>(lower, upper, out, n);
}